// Round 1
// baseline (561.626 us; speedup 1.0000x reference)
//
#include <hip/hip_runtime.h>
#include <hip/hip_bf16.h>

typedef __attribute__((ext_vector_type(8))) short short8v;
typedef __attribute__((ext_vector_type(4))) float float4v;

struct SedTab { signed char sgn[256]; signed char idx[256]; };

__device__ inline unsigned short f2bf(float f) {
    __hip_bfloat16 h = __float2bfloat16(f);
    return *reinterpret_cast<unsigned short*>(&h);
}
__device__ inline float bf2f(unsigned short u) {
    union { unsigned int i; float f; } x; x.i = ((unsigned)u) << 16; return x.f;
}

#define GLOAD_LDS16(g, l) __builtin_amdgcn_global_load_lds( \
    (const __attribute__((address_space(1))) void*)(g), \
    (__attribute__((address_space(3))) void*)(l), 16, 0, 0)

// ---------------- Kernel P: build BigT (n-major) bf16 ----------------
// BigT[n*1536 + k] = sign(t_in,t_out) * w_comp[i][m][c]
// n = t_out*96 + c ; k = t_in*96 + m ; i = unique i with IDX[i,t_in]==t_out
__global__ __launch_bounds__(256) void build_bigT(
    const float* __restrict__ w_comp, unsigned short* __restrict__ bigT, SedTab tab)
{
    int e = blockIdx.x * 256 + threadIdx.x;
    if (e >= 1536 * 1536) return;
    int n = e / 1536, k = e - n * 1536;
    int t_out = n / 96, c = n - t_out * 96;
    int t_in = k / 96, m = k - t_in * 96;
    int i = tab.idx[t_in * 16 + t_out];
    float s = (float)tab.sgn[t_in * 16 + t_out];
    float v = s * w_comp[(i * 96 + m) * 96 + c];
    bigT[e] = f2bf(v);
}

// ---------------- Kernel W: window + cast to bf16 ----------------
// Xw[row][kf], row = (b*64+hh)*64+ww, kf = (s1*4+s2)*96 + m
// block = (b, hh, s1): reads x[b, :, 4hh+s1, :] coalesced, LDS transpose,
// writes contiguous 768B segments per window row.
__global__ __launch_bounds__(256) void window_cast(
    const float* __restrict__ x, unsigned short* __restrict__ xw)
{
    __shared__ unsigned short lds[96][260];
    int blk = blockIdx.x;
    int s1 = blk & 3, hh = (blk >> 2) & 63, b = blk >> 8;
    const float* src = x + (size_t)b * 6291456 + (size_t)(4 * hh + s1) * 256;

    // phase 1: 96 rows x 256 q, float4 loads
    for (int i = threadIdx.x; i < 6144; i += 256) {
        int m = i >> 6;
        int q = (i & 63) << 2;
        float4 v = *(const float4*)(src + (size_t)m * 65536 + q);
        lds[m][q + 0] = f2bf(v.x);
        lds[m][q + 1] = f2bf(v.y);
        lds[m][q + 2] = f2bf(v.z);
        lds[m][q + 3] = f2bf(v.w);
    }
    __syncthreads();
    // phase 2: (ww, group) pairs; group g -> s2 = g/12, mg = (g%12)*8
    size_t rowbase = (size_t)((b * 64 + hh) * 64) * 1536 + (size_t)s1 * 384;
    for (int i = threadIdx.x; i < 3072; i += 256) {
        int ww = i / 48, g = i - ww * 48;
        int s2 = g / 12, mg = (g - s2 * 12) * 8;
        int qq = 4 * ww + s2;
        short8v pk;
        #pragma unroll
        for (int j = 0; j < 8; ++j) pk[j] = (short)lds[mg + j][qq];
        *(short8v*)(xw + rowbase + (size_t)ww * 1536 + s2 * 96 + mg) = pk;
    }
}

// ---------------- Kernel G: bf16 GEMM (M=32768,N=1536,K=1536) + GELU ----------------
// A = Xw row-major [M][K]; Bt = BigT [n][k] (so B-frag reads are k-contiguous).
// m97-style: 128x128 tile, BK=64, 4 waves (2x2), global_load_lds width 16.
__global__ __launch_bounds__(256, 2) void gemm_sed(
    const unsigned short* __restrict__ A,
    const unsigned short* __restrict__ Bt,
    unsigned short* __restrict__ Yg)
{
    __shared__ unsigned short As[128 * 64];
    __shared__ unsigned short Bs[128 * 64];
    const int t = threadIdx.x;
    const int lane = t & 63;
    const int w = t >> 6;
    const int wm = w >> 1, wn = w & 1;
    const int mt = blockIdx.x / 12, nt = blockIdx.x - mt * 12;
    const int m0 = mt * 128, n0 = nt * 128;
    const int lr = lane & 15;
    const int lk = (lane >> 4) << 3;

    float4v acc[4][4];
    #pragma unroll
    for (int i = 0; i < 4; ++i)
        #pragma unroll
        for (int j = 0; j < 4; ++j) acc[i][j] = (float4v)0.0f;

    for (int k0 = 0; k0 < 1536; k0 += 64) {
        __syncthreads();   // previous compute's ds_reads drained before overwrite
        #pragma unroll
        for (int i = 0; i < 4; ++i) {
            const int c = t + i * 256;
            const int row = c >> 3, kc = (c & 7) << 3;
            GLOAD_LDS16(A + (size_t)(m0 + row) * 1536 + k0 + kc, (char*)As + c * 16);
            GLOAD_LDS16(Bt + (size_t)(n0 + row) * 1536 + k0 + kc, (char*)Bs + c * 16);
        }
        __syncthreads();   // implies s_waitcnt vmcnt(0): staged data visible
        #pragma unroll
        for (int kk = 0; kk < 64; kk += 32) {
            short8v af[4], bf[4];
            #pragma unroll
            for (int f = 0; f < 4; ++f)
                af[f] = *(const short8v*)(As + (wm * 64 + f * 16 + lr) * 64 + kk + lk);
            #pragma unroll
            for (int f = 0; f < 4; ++f)
                bf[f] = *(const short8v*)(Bs + (wn * 64 + f * 16 + lr) * 64 + kk + lk);
            #pragma unroll
            for (int mf = 0; mf < 4; ++mf)
                #pragma unroll
                for (int nf = 0; nf < 4; ++nf)
                    acc[mf][nf] = __builtin_amdgcn_mfma_f32_16x16x32_bf16(
                        af[mf], bf[nf], acc[mf][nf], 0, 0, 0);
        }
    }

    // epilogue: exact GELU, cast bf16, store
    #pragma unroll
    for (int mf = 0; mf < 4; ++mf) {
        #pragma unroll
        for (int r = 0; r < 4; ++r) {
            const int gm = m0 + wm * 64 + mf * 16 + (lane >> 4) * 4 + r;
            #pragma unroll
            for (int nf = 0; nf < 4; ++nf) {
                const int gn = n0 + wn * 64 + nf * 16 + lr;
                float v = acc[mf][nf][r];
                float g = 0.5f * v * (1.0f + erff(v * 0.70710678118654752f));
                Yg[(size_t)gm * 1536 + gn] = f2bf(g);
            }
        }
    }
}

// ---------------- Kernel R: projection + bias + NCHW scatter ----------------
// block = (b, hh, s1); thread = q in [0,256). Reads gelu'd Yg, computes
// out[b, :, 4hh+s1, q] = gy @ proj_w^T + proj_b with coalesced 1KB row stores.
__global__ __launch_bounds__(256) void proj_out(
    const unsigned short* __restrict__ Yg,
    const float* __restrict__ pw, const float* __restrict__ pb,
    float* __restrict__ out)
{
    __shared__ float pws[96 * 96];
    __shared__ float pbs[96];
    int blk = blockIdx.x;
    int s1 = blk & 3, hh = (blk >> 2) & 63, b = blk >> 8;
    int q = threadIdx.x;
    int ww = q >> 2, s2 = q & 3;

    for (int i = threadIdx.x; i < 9216; i += 256) pws[i] = pw[i];
    if (threadIdx.x < 96) pbs[threadIdx.x] = pb[threadIdx.x];

    float gy[96];
    size_t rbase = (size_t)((b * 64 + hh) * 64 + ww) * 1536 + (size_t)s1 * 384 + s2 * 96;
    #pragma unroll
    for (int j = 0; j < 12; ++j) {
        short8v v = *(const short8v*)(Yg + rbase + j * 8);
        #pragma unroll
        for (int e = 0; e < 8; ++e)
            gy[j * 8 + e] = bf2f((unsigned short)v[e]);
    }
    __syncthreads();

    int p = 4 * hh + s1;
    size_t obase = (size_t)b * 6291456 + (size_t)p * 256 + q;
    for (int co = 0; co < 96; ++co) {
        float s = pbs[co];
        const float* pr = &pws[co * 96];
        #pragma unroll
        for (int c4 = 0; c4 < 24; ++c4) {
            float4 p4 = *(const float4*)(pr + c4 * 4);
            s += gy[c4 * 4 + 0] * p4.x + gy[c4 * 4 + 1] * p4.y
               + gy[c4 * 4 + 2] * p4.z + gy[c4 * 4 + 3] * p4.w;
        }
        out[obase + (size_t)co * 65536] = s;
    }
}

// ---------------- host: Cayley-Dickson table ----------------
static void cd_table(int n, int* S, int* K) {
    if (n == 1) { S[0] = 1; K[0] = 0; return; }
    int m = n / 2;
    int s[64], k[64];   // max 8x8 for n=16 recursion
    cd_table(m, s, k);
    for (int i = 0; i < n; ++i) {
        for (int j = 0; j < n; ++j) {
            int cj, cq;
            if (i < m && j < m) { S[i*n+j] = s[i*m+j]; K[i*n+j] = k[i*m+j]; }
            else if (i < m) { int q = j - m; S[i*n+j] = s[q*m+i]; K[i*n+j] = m + k[q*m+i]; }
            else if (j < m) { int p = i - m; cj = (j == 0) ? 1 : -1;
                              S[i*n+j] = s[p*m+j] * cj; K[i*n+j] = m + k[p*m+j]; }
            else { int p = i - m, q = j - m; cq = (q == 0) ? 1 : -1;
                   S[i*n+j] = -cq * s[q*m+p]; K[i*n+j] = k[q*m+p]; }
        }
    }
}

extern "C" void kernel_launch(void* const* d_in, const int* in_sizes, int n_in,
                              void* d_out, int out_size, void* d_ws, size_t ws_size,
                              hipStream_t stream) {
    const float* x      = (const float*)d_in[0];
    const float* w_comp = (const float*)d_in[1];
    const float* proj_w = (const float*)d_in[2];
    const float* proj_b = (const float*)d_in[3];
    float* out = (float*)d_out;

    // ws layout: BigT bf16 (4,718,592 B) | Yg bf16 (100,663,296 B)
    unsigned short* BigT = (unsigned short*)d_ws;
    unsigned short* Yg   = (unsigned short*)((char*)d_ws + 4718592);
    // Xw bf16 (100,663,296 B) lives in d_out as scratch; R fully overwrites d_out later.
    unsigned short* Xw   = (unsigned short*)d_out;

    // host: sedenion table + inverse lookup (t_in, t_out) -> (i, sign)
    int S16[256], K16[256];
    cd_table(16, S16, K16);
    SedTab tab;
    for (int i = 0; i < 16; ++i)
        for (int j = 0; j < 16; ++j) {
            int k = K16[i * 16 + j];
            tab.idx[j * 16 + k] = (signed char)i;
            tab.sgn[j * 16 + k] = (signed char)S16[i * 16 + j];
        }

    hipLaunchKernelGGL(build_bigT, dim3(9216), dim3(256), 0, stream, w_comp, BigT, tab);
    hipLaunchKernelGGL(window_cast, dim3(2048), dim3(256), 0, stream, x, Xw);
    hipLaunchKernelGGL(gemm_sed, dim3(3072), dim3(256), 0, stream, Xw, BigT, Yg);
    hipLaunchKernelGGL(proj_out, dim3(2048), dim3(256), 0, stream, Yg, proj_w, proj_b, out);
}

// Round 2
// 349.996 us; speedup vs baseline: 1.6047x; 1.6047x over previous
//
#include <hip/hip_runtime.h>
#include <hip/hip_bf16.h>

typedef __attribute__((ext_vector_type(8))) short short8v;
typedef __attribute__((ext_vector_type(4))) float float4v;

struct SedTab { signed char sgn[256]; signed char idx[256]; };

__device__ inline unsigned short f2bf(float f) {
    __hip_bfloat16 h = __float2bfloat16(f);
    return *reinterpret_cast<unsigned short*>(&h);
}
__device__ inline float bf2f(unsigned short u) {
    union { unsigned int i; float f; } x; x.i = ((unsigned)u) << 16; return x.f;
}

#define GLOAD_LDS16(g, l) __builtin_amdgcn_global_load_lds( \
    (const __attribute__((address_space(1))) void*)(g), \
    (__attribute__((address_space(3))) void*)(l), 16, 0, 0)

// ---------------- Kernel P: build BigT (n-major) bf16 ----------------
__global__ __launch_bounds__(256) void build_bigT(
    const float* __restrict__ w_comp, unsigned short* __restrict__ bigT, SedTab tab)
{
    int e = blockIdx.x * 256 + threadIdx.x;
    if (e >= 1536 * 1536) return;
    int n = e / 1536, k = e - n * 1536;
    int t_out = n / 96, c = n - t_out * 96;
    int t_in = k / 96, m = k - t_in * 96;
    int i = tab.idx[t_in * 16 + t_out];
    float s = (float)tab.sgn[t_in * 16 + t_out];
    float v = s * w_comp[(i * 96 + m) * 96 + c];
    bigT[e] = f2bf(v);
}

// ---------------- Kernel W: window + cast to bf16 ----------------
__global__ __launch_bounds__(256) void window_cast(
    const float* __restrict__ x, unsigned short* __restrict__ xw)
{
    __shared__ unsigned short lds[96][260];
    int blk = blockIdx.x;
    int s1 = blk & 3, hh = (blk >> 2) & 63, b = blk >> 8;
    const float* src = x + (size_t)b * 6291456 + (size_t)(4 * hh + s1) * 256;

    for (int i = threadIdx.x; i < 6144; i += 256) {
        int m = i >> 6;
        int q = (i & 63) << 2;
        float4 v = *(const float4*)(src + (size_t)m * 65536 + q);
        lds[m][q + 0] = f2bf(v.x);
        lds[m][q + 1] = f2bf(v.y);
        lds[m][q + 2] = f2bf(v.z);
        lds[m][q + 3] = f2bf(v.w);
    }
    __syncthreads();
    size_t rowbase = (size_t)((b * 64 + hh) * 64) * 1536 + (size_t)s1 * 384;
    for (int i = threadIdx.x; i < 3072; i += 256) {
        int ww = i / 48, g = i - ww * 48;
        int s2 = g / 12, mg = (g - s2 * 12) * 8;
        int qq = 4 * ww + s2;
        short8v pk;
        #pragma unroll
        for (int j = 0; j < 8; ++j) pk[j] = (short)lds[mg + j][qq];
        *(short8v*)(xw + rowbase + (size_t)ww * 1536 + s2 * 96 + mg) = pk;
    }
}

// ---------------- Kernel G: bf16 GEMM (M=32768,N=1536,K=1536) + GELU ----------------
__global__ __launch_bounds__(256, 2) void gemm_sed(
    const unsigned short* __restrict__ A,
    const unsigned short* __restrict__ Bt,
    unsigned short* __restrict__ Yg)
{
    __shared__ unsigned short As[128 * 64];
    __shared__ unsigned short Bs[128 * 64];
    const int t = threadIdx.x;
    const int lane = t & 63;
    const int w = t >> 6;
    const int wm = w >> 1, wn = w & 1;
    const int mt = blockIdx.x / 12, nt = blockIdx.x - mt * 12;
    const int m0 = mt * 128, n0 = nt * 128;
    const int lr = lane & 15;
    const int lk = (lane >> 4) << 3;

    float4v acc[4][4];
    #pragma unroll
    for (int i = 0; i < 4; ++i)
        #pragma unroll
        for (int j = 0; j < 4; ++j) acc[i][j] = (float4v)0.0f;

    for (int k0 = 0; k0 < 1536; k0 += 64) {
        __syncthreads();
        #pragma unroll
        for (int i = 0; i < 4; ++i) {
            const int c = t + i * 256;
            const int row = c >> 3, kc = (c & 7) << 3;
            GLOAD_LDS16(A + (size_t)(m0 + row) * 1536 + k0 + kc, (char*)As + c * 16);
            GLOAD_LDS16(Bt + (size_t)(n0 + row) * 1536 + k0 + kc, (char*)Bs + c * 16);
        }
        __syncthreads();
        #pragma unroll
        for (int kk = 0; kk < 64; kk += 32) {
            short8v af[4], bf[4];
            #pragma unroll
            for (int f = 0; f < 4; ++f)
                af[f] = *(const short8v*)(As + (wm * 64 + f * 16 + lr) * 64 + kk + lk);
            #pragma unroll
            for (int f = 0; f < 4; ++f)
                bf[f] = *(const short8v*)(Bs + (wn * 64 + f * 16 + lr) * 64 + kk + lk);
            #pragma unroll
            for (int mf = 0; mf < 4; ++mf)
                #pragma unroll
                for (int nf = 0; nf < 4; ++nf)
                    acc[mf][nf] = __builtin_amdgcn_mfma_f32_16x16x32_bf16(
                        af[mf], bf[nf], acc[mf][nf], 0, 0, 0);
        }
    }

    #pragma unroll
    for (int mf = 0; mf < 4; ++mf) {
        #pragma unroll
        for (int r = 0; r < 4; ++r) {
            const int gm = m0 + wm * 64 + mf * 16 + (lane >> 4) * 4 + r;
            #pragma unroll
            for (int nf = 0; nf < 4; ++nf) {
                const int gn = n0 + wn * 64 + nf * 16 + lr;
                float v = acc[mf][nf][r];
                float g = 0.5f * v * (1.0f + erff(v * 0.70710678118654752f));
                Yg[(size_t)gm * 1536 + gn] = f2bf(g);
            }
        }
    }
}

// ---------------- Kernel R: MFMA projection + bias + NCHW store ----------------
// block = (b, hh, s1). Computes out[b, :, p=4hh+s1, :] (96 x 256 f32).
// D[c_out][q] = sum_c pw[c_out][c] * gy[q][c]  via mfma_f32_16x16x32_bf16:
//   A-frag: pws[c_out][k]  (row-major, same pattern as gemm's As)
//   B-frag: gys[q][k]      (n-major [n][k], same pattern as gemm's Bs)
// LDS stride 104 shorts = 208 B (16B-aligned, 2-way banks = free).
__global__ __launch_bounds__(256, 2) void proj_mfma(
    const unsigned short* __restrict__ Yg,
    const float* __restrict__ pw, const float* __restrict__ pb,
    float* __restrict__ out)
{
    __shared__ unsigned short gys[256 * 104];
    __shared__ unsigned short pws[96 * 104];
    __shared__ float pbs[96];

    const int blk = blockIdx.x;
    const int s1 = blk & 3, hh = (blk >> 2) & 63, b = blk >> 8;
    const int t = threadIdx.x;
    const int lane = t & 63, w = t >> 6;
    const int lr = lane & 15;

    // stage pw (96x96 f32 -> bf16)
    for (int i = t; i < 9216; i += 256) {
        int r = i / 96, c = i - r * 96;
        pws[r * 104 + c] = f2bf(pw[i]);
    }
    if (t < 96) pbs[t] = pb[t];

    // stage gy: per ww, 384 contiguous bf16 (s2=0..3, c=0..95) from Yg
    size_t rowbase = (size_t)((b * 64 + hh) * 64) * 1536 + (size_t)s1 * 384;
    for (int i = t; i < 3072; i += 256) {
        int ww = i / 48, v = i - ww * 48;
        short8v pk = *(const short8v*)(Yg + rowbase + (size_t)ww * 1536 + v * 8);
        int s2 = v / 12;
        int c = (v - s2 * 12) * 8;
        int q = 4 * ww + s2;
        *(short8v*)(&gys[q * 104 + c]) = pk;
    }
    __syncthreads();

    // MFMA: M=96 (c_out, 6 frags), N=256 (q, 4 waves x 4 frags), K=96 (3 steps)
    float4v acc[6][4];
    #pragma unroll
    for (int i = 0; i < 6; ++i)
        #pragma unroll
        for (int j = 0; j < 4; ++j) acc[i][j] = (float4v)0.0f;

    #pragma unroll
    for (int ks = 0; ks < 3; ++ks) {
        const int lk = ks * 32 + ((lane >> 4) << 3);
        short8v af[6], bf[4];
        #pragma unroll
        for (int mf = 0; mf < 6; ++mf)
            af[mf] = *(const short8v*)(&pws[(mf * 16 + lr) * 104 + lk]);
        #pragma unroll
        for (int nf = 0; nf < 4; ++nf)
            bf[nf] = *(const short8v*)(&gys[(w * 64 + nf * 16 + lr) * 104 + lk]);
        #pragma unroll
        for (int mf = 0; mf < 6; ++mf)
            #pragma unroll
            for (int nf = 0; nf < 4; ++nf)
                acc[mf][nf] = __builtin_amdgcn_mfma_f32_16x16x32_bf16(
                    af[mf], bf[nf], acc[mf][nf], 0, 0, 0);
    }

    // epilogue: bias + store. col q = w*64 + nf*16 + lr (coalesced 64B runs)
    const int p = 4 * hh + s1;
    const size_t obase = (size_t)b * 6291456 + (size_t)p * 256;
    #pragma unroll
    for (int mf = 0; mf < 6; ++mf) {
        #pragma unroll
        for (int r = 0; r < 4; ++r) {
            const int c = mf * 16 + (lane >> 4) * 4 + r;
            const float bias = pbs[c];
            #pragma unroll
            for (int nf = 0; nf < 4; ++nf) {
                const int q = w * 64 + nf * 16 + lr;
                out[obase + (size_t)c * 65536 + q] = acc[mf][nf][r] + bias;
            }
        }
    }
}

// ---------------- host: Cayley-Dickson table ----------------
static void cd_table(int n, int* S, int* K) {
    if (n == 1) { S[0] = 1; K[0] = 0; return; }
    int m = n / 2;
    int s[64], k[64];
    cd_table(m, s, k);
    for (int i = 0; i < n; ++i) {
        for (int j = 0; j < n; ++j) {
            if (i < m && j < m) { S[i*n+j] = s[i*m+j]; K[i*n+j] = k[i*m+j]; }
            else if (i < m) { int q = j - m; S[i*n+j] = s[q*m+i]; K[i*n+j] = m + k[q*m+i]; }
            else if (j < m) { int p = i - m; int cj = (j == 0) ? 1 : -1;
                              S[i*n+j] = s[p*m+j] * cj; K[i*n+j] = m + k[p*m+j]; }
            else { int p = i - m, q = j - m; int cq = (q == 0) ? 1 : -1;
                   S[i*n+j] = -cq * s[q*m+p]; K[i*n+j] = k[q*m+p]; }
        }
    }
}

extern "C" void kernel_launch(void* const* d_in, const int* in_sizes, int n_in,
                              void* d_out, int out_size, void* d_ws, size_t ws_size,
                              hipStream_t stream) {
    const float* x      = (const float*)d_in[0];
    const float* w_comp = (const float*)d_in[1];
    const float* proj_w = (const float*)d_in[2];
    const float* proj_b = (const float*)d_in[3];
    float* out = (float*)d_out;

    unsigned short* BigT = (unsigned short*)d_ws;
    unsigned short* Yg   = (unsigned short*)((char*)d_ws + 4718592);
    unsigned short* Xw   = (unsigned short*)d_out;   // scratch; overwritten by proj_mfma

    int S16[256], K16[256];
    cd_table(16, S16, K16);
    SedTab tab;
    for (int i = 0; i < 16; ++i)
        for (int j = 0; j < 16; ++j) {
            int k = K16[i * 16 + j];
            tab.idx[j * 16 + k] = (signed char)i;
            tab.sgn[j * 16 + k] = (signed char)S16[i * 16 + j];
        }

    hipLaunchKernelGGL(build_bigT, dim3(9216), dim3(256), 0, stream, w_comp, BigT, tab);
    hipLaunchKernelGGL(window_cast, dim3(2048), dim3(256), 0, stream, x, Xw);
    hipLaunchKernelGGL(gemm_sed, dim3(3072), dim3(256), 0, stream, Xw, BigT, Yg);
    hipLaunchKernelGGL(proj_mfma, dim3(2048), dim3(256), 0, stream, Yg, proj_w, proj_b, out);
}